// Round 8
// baseline (441.465 us; speedup 1.0000x reference)
//
#include <hip/hip_runtime.h>
#include <hip/hip_bf16.h>

// Problem constants
#define BB 32   // batch
#define TT 32   // window
#define NN 64   // num_series
#define CC 64   // inter_dim
#define HH 64   // gru hidden
#define QKD 32  // qk dim
#define HOR 12
#define OUTD (NN*HOR)        // 768
#define KFLAT (NN*CC*TT)     // 131072

typedef __attribute__((ext_vector_type(4))) float f32x4;
typedef __attribute__((ext_vector_type(8))) short s16x8;
typedef unsigned short ush;

static __device__ __forceinline__ ush f2bf(float f) {
    unsigned u = __float_as_uint(f);
    unsigned r = (u + 0x7FFFu + ((u >> 16) & 1u)) >> 16;
    return (ush)r;
}
static __device__ __forceinline__ float bf2f(ush h) {
    return __uint_as_float(((unsigned)h) << 16);
}
static __device__ __forceinline__ void split8(const float* f, uint4& hi, uint4& lo) {
    unsigned hh[8], ll[8];
    #pragma unroll
    for (int i = 0; i < 8; ++i) {
        ush h = f2bf(f[i]);
        float hf = bf2f(h);
        hh[i] = h;
        ll[i] = f2bf(f[i] - hf);
    }
    hi = make_uint4(hh[0] | (hh[1] << 16), hh[2] | (hh[3] << 16),
                    hh[4] | (hh[5] << 16), hh[6] | (hh[7] << 16));
    lo = make_uint4(ll[0] | (ll[1] << 16), ll[2] | (ll[3] << 16),
                    ll[4] | (ll[5] << 16), ll[6] | (ll[7] << 16));
}
static __device__ __forceinline__ void gl2lds16(const void* gsrc, void* ldst) {
    __builtin_amdgcn_global_load_lds(
        (const __attribute__((address_space(1))) unsigned int*)gsrc,
        (__attribute__((address_space(3))) unsigned int*)ldst, 16, 0, 0);
}

// ---------------- prep (blocks<320) + GRU (all 512 blocks) -----------------
__global__ __launch_bounds__(256) void prep_gru_kernel(
    const float* __restrict__ x, const float* __restrict__ wih,
    const float* __restrict__ whh, const float* __restrict__ bih,
    const float* __restrict__ bhh, float* __restrict__ hT,
    const float* __restrict__ gw0, const float* __restrict__ wx, const float* __restrict__ bx,
    float* __restrict__ u, float* __restrict__ v,
    const float* __restrict__ gw1, ush* __restrict__ g1h, ush* __restrict__ g1l,
    const float* __restrict__ gw2, ush* __restrict__ g2h, ush* __restrict__ g2l,
    const float* __restrict__ cw2, ush* __restrict__ c2h, ush* __restrict__ c2l,
    const float* __restrict__ cw3, ush* __restrict__ c3h, ush* __restrict__ c3l,
    const float* __restrict__ lb, float* __restrict__ out)
{
    __shared__ __align__(16) char smem[17408];
    int bid = blockIdx.x, tid = threadIdx.x;

    // ---- phase A: prep ----
    if (bid < 32) {                       // u/v rank-1 prep, t=bid
        float (*pu)[64] = (float(*)[64])smem;
        float (*pv)[64] = (float(*)[64])(smem + 1024);
        int t = bid, d = tid & 63, cq = tid >> 6;
        float su = 0.f, sv = 0.f;
        for (int c = cq*16; c < cq*16 + 16; ++c) {
            float gv = gw0[t*4096 + c*64 + d];
            su += wx[c]*gv; sv += bx[c]*gv;
        }
        pu[cq][d] = su; pv[cq][d] = sv;
        __syncthreads();
        if (tid < 64) {
            u[t*64 + tid] = pu[0][tid]+pu[1][tid]+pu[2][tid]+pu[3][tid];
            v[t*64 + tid] = pv[0][tid]+pv[1][tid]+pv[2][tid]+pv[3][tid];
        }
    } else if (bid < 96) {                // gwT split
        const float* gw = (bid < 64) ? gw1 : gw2;
        ush* hi = (bid < 64) ? g1h : g2h;
        ush* lo = (bid < 64) ? g1l : g2l;
        int t = (bid < 64) ? bid - 32 : bid - 64;
        for (int idx = tid; idx < 4096; idx += 256) {
            int d = idx >> 6, c = idx & 63;
            float val = gw[t*4096 + c*64 + d];
            ush h = f2bf(val);
            hi[t*4096 + idx] = h;
            lo[t*4096 + idx] = f2bf(val - bf2f(h));
        }
    } else if (bid < 224) {               // conv weight split (cw2, cw3 only)
        const float* cw; ush *hi, *lo; int KW, co;
        if (bid < 160) { cw = cw2; hi = c2h; lo = c2l; KW = 5; co = bid - 96; }
        else           { cw = cw3; hi = c3h; lo = c3l; KW = 7; co = bid - 160; }
        int K = KW*64;
        for (int idx = tid; idx < K; idx += 256) {
            int ka = idx >> 6, ci = idx & 63;
            float val = cw[(size_t)(co*64 + ci)*KW + ka];
            ush h = f2bf(val);
            hi[(size_t)co*K + idx] = h;
            lo[(size_t)co*K + idx] = f2bf(val - bf2f(h));
        }
    } else if (bid < 320) {               // out init with bias (96 blocks)
        int idx = (bid - 224)*256 + tid;
        out[idx] = lb[idx % OUTD];
    }
    __syncthreads();

    // ---- phase B: GRU ----
    {
        float (*hbuf)[64] = (float(*)[64])smem;       // 1 KB
        float4* part = (float4*)(smem + 1024);        // 16 KB
        int w = tid >> 6, j = tid & 63;
        float Wreg[3][16];
        #pragma unroll
        for (int g = 0; g < 3; ++g)
            #pragma unroll
            for (int q = 0; q < 4; ++q) {
                float4 wv = *(const float4*)&whh[(g*64 + j)*64 + w*16 + q*4];
                Wreg[g][q*4+0] = wv.x; Wreg[g][q*4+1] = wv.y;
                Wreg[g][q*4+2] = wv.z; Wreg[g][q*4+3] = wv.w;
            }
        hbuf[w][j] = 0.0f;
        int gs0 = bid * 4;
        int b = gs0 >> 6, n0 = gs0 & 63;
        float wih_r = wih[j], wih_z = wih[64+j], wih_n = wih[128+j];
        float bi_r = bih[j], bi_z = bih[64+j], bi_n = bih[128+j];
        float bh_r = bhh[j], bh_z = bhh[64+j], bh_n = bhh[128+j];
        __syncthreads();
        float hreg = 0.0f;
        for (int t = 0; t < TT; ++t) {
            float p[3][4];
            #pragma unroll
            for (int g = 0; g < 3; ++g)
                #pragma unroll
                for (int s = 0; s < 4; ++s) p[g][s] = 0.f;
            #pragma unroll
            for (int s = 0; s < 4; ++s) {
                #pragma unroll
                for (int q = 0; q < 4; ++q) {
                    const float4 hv = *(const float4*)&hbuf[s][w*16 + q*4];
                    #pragma unroll
                    for (int g = 0; g < 3; ++g) {
                        p[g][s] += hv.x*Wreg[g][q*4]   + hv.y*Wreg[g][q*4+1]
                                 + hv.z*Wreg[g][q*4+2] + hv.w*Wreg[g][q*4+3];
                    }
                }
            }
            #pragma unroll
            for (int s = 0; s < 4; ++s)
                part[(w*4 + s)*64 + j] = make_float4(p[0][s], p[1][s], p[2][s], 0.f);
            __syncthreads();
            float4 q0 = part[(0*4 + w)*64 + j];
            float4 q1 = part[(1*4 + w)*64 + j];
            float4 q2 = part[(2*4 + w)*64 + j];
            float4 q3 = part[(3*4 + w)*64 + j];
            float gr = bh_r + q0.x + q1.x + q2.x + q3.x;
            float gz = bh_z + q0.y + q1.y + q2.y + q3.y;
            float gn = bh_n + q0.z + q1.z + q2.z + q3.z;
            float xt = x[(b*TT + t)*NN + n0 + w];
            float r = 1.f/(1.f+__expf(-(xt*wih_r + bi_r + gr)));
            float z = 1.f/(1.f+__expf(-(xt*wih_z + bi_z + gz)));
            float nn_ = tanhf(xt*wih_n + bi_n + r*gn);
            float hnew = (1.f - z)*nn_ + z*hreg;
            hreg = hnew;
            hbuf[w][j] = hnew;
            __syncthreads();
        }
        hT[(gs0 + w)*64 + j] = hreg;
    }
}

// ---------------- attention + s/dg + stage1 tables -------------------------
// blocks 0..31: per-batch attn -> whT hi/lo, s[b][t][j], dg[b][j]
// block 32: Au/Av/Ag tables for the collapsed stage 1
__global__ __launch_bounds__(256) void attn_kernel(
    const float* __restrict__ hT, const float* __restrict__ wq_w,
    const float* __restrict__ wq_b, const float* __restrict__ wk_w,
    const float* __restrict__ wk_b,
    ush* __restrict__ whT_hi, ush* __restrict__ whT_lo,
    const float* __restrict__ x, float* __restrict__ sbuf, float* __restrict__ dgbuf,
    const float* __restrict__ u, const float* __restrict__ v,
    const float* __restrict__ cw1, const float* __restrict__ gb0,
    float* __restrict__ Au, float* __restrict__ Av, float* __restrict__ Ag)
{
    int b = blockIdx.x, tid = threadIdx.x;
    if (b == 32) {   // tables: A*[ka][t][co] = sum_ci cw1[co][ci][ka] * {u,v,gb0}[t][ci]
        for (int idx = tid; idx < 3*32*64; idx += 256) {
            int ka = idx >> 11;            // idx/(32*64)
            int t  = (idx >> 6) & 31;
            int co = idx & 63;
            float au_ = 0.f, av_ = 0.f, ag_ = 0.f;
            for (int ci = 0; ci < 64; ++ci) {
                float w_ = cw1[(size_t)(co*64 + ci)*3 + ka];
                au_ += w_ * u[t*64 + ci];
                av_ += w_ * v[t*64 + ci];
                ag_ += w_ * gb0[t*64 + ci];
            }
            Au[idx] = au_; Av[idx] = av_; Ag[idx] = ag_;
        }
        return;
    }
    __shared__ float hs[64][64];                 // reused as xl[32][64] later
    __shared__ float Qs[64][33], Ks[64][33];
    __shared__ float S[64][65];
    __shared__ float pd[4][64];
    __shared__ float dinv[64];
    float (*xl)[64] = (float(*)[64])hs;
    for (int idx = tid; idx < 64*64; idx += 256) hs[idx>>6][idx&63] = hT[b*4096 + idx];
    __syncthreads();
    for (int idx = tid; idx < 64*32; idx += 256) {
        int n_ = idx >> 5, q = idx & 31;
        float accq = wq_b[q], acck = wk_b[q];
        #pragma unroll 8
        for (int h_ = 0; h_ < 64; ++h_) {
            float hv = hs[n_][h_];
            accq += hv * wq_w[q*64 + h_];
            acck += hv * wk_w[q*64 + h_];
        }
        Qs[n_][q] = accq; Ks[n_][q] = acck;
    }
    __syncthreads();
    const float scale = 0.17677669529663687f; // 1/sqrt(32)
    for (int idx = tid; idx < 64*64; idx += 256) {
        int n_ = idx >> 6, m = idx & 63;
        float acc = 0.f;
        #pragma unroll 8
        for (int q = 0; q < 32; ++q) acc += Qs[n_][q]*Ks[m][q];
        S[n_][m] = acc * scale;
    }
    __syncthreads();
    // hs no longer needed -> load x tile into its space
    for (int idx = tid; idx < 32*64; idx += 256) {
        int t = idx >> 6, i = idx & 63;
        xl[t][i] = x[(b*TT + t)*NN + i];
    }
    {   // row softmax: 4 lanes per row
        int r = tid >> 2, q = tid & 3;
        float mx = -1e30f;
        #pragma unroll
        for (int m = 0; m < 16; ++m) mx = fmaxf(mx, S[r][q*16+m]);
        mx = fmaxf(mx, __shfl_xor(mx, 1));
        mx = fmaxf(mx, __shfl_xor(mx, 2));
        float sum = 0.f;
        float e[16];
        #pragma unroll
        for (int m = 0; m < 16; ++m) { e[m] = __expf(S[r][q*16+m]-mx); sum += e[m]; }
        sum += __shfl_xor(sum, 1);
        sum += __shfl_xor(sum, 2);
        float inv = 1.f/sum;
        #pragma unroll
        for (int m = 0; m < 16; ++m) S[r][q*16+m] = e[m]*inv;
    }
    __syncthreads();
    {   // column degree of softmax matrix
        int c = tid & 63, rq = tid >> 6;
        float d = 0.f;
        #pragma unroll
        for (int i = 0; i < 16; ++i) d += S[rq*16 + i][c];
        pd[rq][c] = d;
    }
    __syncthreads();
    if (tid < 64) {
        float d = pd[0][tid]+pd[1][tid]+pd[2][tid]+pd[3][tid];
        dinv[tid] = (d > 0.f) ? 1.0f/sqrtf(d) : 0.f;
    }
    __syncthreads();
    // R[i][j] = dinv[i]*S[i][j]  (in place)
    for (int idx = tid; idx < 64*64; idx += 256) {
        int i = idx >> 6, j = idx & 63;
        S[i][j] *= dinv[i];
    }
    __syncthreads();
    // whT[j][i] = R[i][j]*dinv[j]
    for (int idx = tid; idx < 64*64; idx += 256) {
        int jj = idx >> 6, ii = idx & 63;
        float val = S[ii][jj]*dinv[jj];
        ush h = f2bf(val);
        whT_hi[b*4096 + idx] = h;
        whT_lo[b*4096 + idx] = f2bf(val - bf2f(h));
    }
    // dg[j] = dinv[j] * sum_i R[i][j]
    {
        int c = tid & 63, rq = tid >> 6;
        float d = 0.f;
        #pragma unroll
        for (int i = 0; i < 16; ++i) d += S[rq*16 + i][c];
        pd[rq][c] = d;
    }
    __syncthreads();
    if (tid < 64) {
        dgbuf[b*64 + tid] = dinv[tid]*(pd[0][tid]+pd[1][tid]+pd[2][tid]+pd[3][tid]);
    }
    // s[b][t][j] = dinv[j] * sum_i R[i][j]*x[t][i]
    {
        int j = tid & 63, tq = tid >> 6;
        float acc[8];
        #pragma unroll
        for (int uu = 0; uu < 8; ++uu) acc[uu] = 0.f;
        for (int i = 0; i < 64; ++i) {
            float rv = S[i][j];
            #pragma unroll
            for (int uu = 0; uu < 8; ++uu)
                acc[uu] += rv * xl[tq*8 + uu][i];
        }
        float dj = dinv[j];
        #pragma unroll
        for (int uu = 0; uu < 8; ++uu)
            sbuf[(b*32 + tq*8 + uu)*64 + j] = acc[uu] * dj;
    }
}

// ---------------- collapsed stage 1: rank-1 gcn + conv1 + leaky ------------
// out[b,n,co,t] = leaky( cb[co] + sum_ka s[b,t',n]*Au[ka][t'][co]
//                                + dg[b,n]*Av[ka][t'][co] + Ag[ka][t'][co] ), t'=t+ka-1
__global__ __launch_bounds__(256) void fused1_kernel(
    const float* __restrict__ sbuf, const float* __restrict__ dgbuf,
    const float* __restrict__ Au, const float* __restrict__ Av, const float* __restrict__ Ag,
    const float* __restrict__ cb1, float* __restrict__ o)
{
    __shared__ float sl[32];
    __shared__ float dgl;
    int bn = blockIdx.x, b = bn >> 6, n = bn & 63;
    int tid = threadIdx.x;
    if (tid < 32) sl[tid] = sbuf[(b*32 + tid)*64 + n];
    if (tid == 32) dgl = dgbuf[b*64 + n];
    __syncthreads();
    int co = tid & 63, tg = tid >> 6;
    float cb = cb1[co];
    float d = dgl;
    #pragma unroll
    for (int uu = 0; uu < 8; ++uu) {
        int t = tg*8 + uu;
        float acc = cb;
        #pragma unroll
        for (int ka = 0; ka < 3; ++ka) {
            int tp = t + ka - 1;
            if (tp >= 0 && tp < 32) {
                int ti = (ka*32 + tp)*64 + co;
                acc += sl[tp]*Au[ti] + d*Av[ti] + Ag[ti];
            }
        }
        acc = (acc >= 0.f) ? acc : 0.01f*acc;
        o[((size_t)t*2048 + bn)*64 + co] = acc;
    }
}

// ---------------- GCN via MFMA (hi/lo split) -------------------------------
__global__ __launch_bounds__(256) void gcn_mfma(
    const float* __restrict__ fin,
    const ush* __restrict__ gwT_hi, const ush* __restrict__ gwT_lo,
    const ush* __restrict__ whT_hi, const ush* __restrict__ whT_lo,
    const float* __restrict__ gb, float* __restrict__ o)
{
    __shared__ __align__(16) ush ft_hi[64][64], ft_lo[64][64];
    __shared__ __align__(16) ush xsT_hi[64][64], xsT_lo[64][64];
    int tb = blockIdx.x, t = tb >> 5, b = tb & 31;
    int tid = threadIdx.x;
    int w = tid >> 6, l = tid & 63, lm = l & 15, ld = l >> 4;

    {
        int row = tid >> 2, c0 = (tid & 3) * 16;
        const float* src = fin + (size_t)tb*4096 + row*64 + c0;
        float f8a[8], f8b[8];
        *(float4*)f8a = *(const float4*)src;       *(float4*)(f8a+4) = *(const float4*)(src+4);
        *(float4*)f8b = *(const float4*)(src+8);   *(float4*)(f8b+4) = *(const float4*)(src+12);
        uint4 hi, lo;
        split8(f8a, hi, lo);
        int u0 = ((c0>>3)) ^ (row & 7);
        *(uint4*)&ft_hi[row][u0*8] = hi; *(uint4*)&ft_lo[row][u0*8] = lo;
        split8(f8b, hi, lo);
        int u1 = ((c0>>3)+1) ^ (row & 7);
        *(uint4*)&ft_hi[row][u1*8] = hi; *(uint4*)&ft_lo[row][u1*8] = lo;
    }
    __syncthreads();
    f32x4 acc[4];
    #pragma unroll
    for (int ct = 0; ct < 4; ++ct) acc[ct] = (f32x4){0.f,0.f,0.f,0.f};
    #pragma unroll
    for (int kc = 0; kc < 2; ++kc) {
        int nrow = w*16 + lm;
        int ux = (kc*4 + ld) ^ (nrow & 7);
        s16x8 xh = *(const s16x8*)&ft_hi[nrow][ux*8];
        s16x8 xl = *(const s16x8*)&ft_lo[nrow][ux*8];
        #pragma unroll
        for (int ct = 0; ct < 4; ++ct) {
            int drow = ct*16 + lm;
            s16x8 yh = *(const s16x8*)&gwT_hi[t*4096 + drow*64 + kc*32 + ld*8];
            s16x8 yl = *(const s16x8*)&gwT_lo[t*4096 + drow*64 + kc*32 + ld*8];
            acc[ct] = __builtin_amdgcn_mfma_f32_16x16x32_bf16(xh, yh, acc[ct], 0, 0, 0);
            acc[ct] = __builtin_amdgcn_mfma_f32_16x16x32_bf16(xh, yl, acc[ct], 0, 0, 0);
            acc[ct] = __builtin_amdgcn_mfma_f32_16x16x32_bf16(xl, yh, acc[ct], 0, 0, 0);
        }
    }
    #pragma unroll
    for (int ct = 0; ct < 4; ++ct) {
        int d = ct*16 + lm;
        int n0 = w*16 + ld*4;
        ush hh[4], llo[4];
        #pragma unroll
        for (int r = 0; r < 4; ++r) {
            float val = acc[ct][r];
            ush h = f2bf(val);
            hh[r] = h; llo[r] = f2bf(val - bf2f(h));
        }
        int un = (n0 >> 3) ^ (d & 7);
        int base = d*64 + un*8 + (n0 & 7);
        *(uint2*)&xsT_hi[0][0 + base] = make_uint2(hh[0]|(hh[1]<<16), hh[2]|(hh[3]<<16));
        *(uint2*)&xsT_lo[0][0 + base] = make_uint2(llo[0]|(llo[1]<<16), llo[2]|(llo[3]<<16));
    }
    __syncthreads();

    f32x4 acc2[4];
    #pragma unroll
    for (int ct = 0; ct < 4; ++ct) acc2[ct] = (f32x4){0.f,0.f,0.f,0.f};
    #pragma unroll
    for (int kc = 0; kc < 2; ++kc) {
        int jrow = w*16 + lm;
        s16x8 wh = *(const s16x8*)&whT_hi[b*4096 + jrow*64 + kc*32 + ld*8];
        s16x8 wl = *(const s16x8*)&whT_lo[b*4096 + jrow*64 + kc*32 + ld*8];
        #pragma unroll
        for (int ct = 0; ct < 4; ++ct) {
            int drow = ct*16 + lm;
            int uy = (kc*4 + ld) ^ (drow & 7);
            s16x8 yh = *(const s16x8*)&xsT_hi[drow][uy*8];
            s16x8 yl = *(const s16x8*)&xsT_lo[drow][uy*8];
            acc2[ct] = __builtin_amdgcn_mfma_f32_16x16x32_bf16(wh, yh, acc2[ct], 0, 0, 0);
            acc2[ct] = __builtin_amdgcn_mfma_f32_16x16x32_bf16(wh, yl, acc2[ct], 0, 0, 0);
            acc2[ct] = __builtin_amdgcn_mfma_f32_16x16x32_bf16(wl, yh, acc2[ct], 0, 0, 0);
        }
    }
    float* oo = o + (size_t)tb*4096;
    #pragma unroll
    for (int ct = 0; ct < 4; ++ct) {
        int d = ct*16 + lm;
        float bias = gb[t*64 + d];
        #pragma unroll
        for (int r = 0; r < 4; ++r) {
            int jj = w*16 + ld*4 + r;
            oo[jj*64 + d] = acc2[ct][r] + bias;
        }
    }
}

// ---------------- temporal conv1d via im2col MFMA + LeakyReLU --------------
template<int KW, bool LAST>
__global__ __launch_bounds__(256) void conv_mfma(float* __restrict__ g,
    const ush* __restrict__ wch, const ush* __restrict__ wcl,
    const float* __restrict__ cb, ush* __restrict__ fo)
{
    constexpr int P = KW/2, K = KW*64, K32 = KW*2;
    __shared__ __align__(16) ush sh[32][64], sl[32][64];
    int bn = blockIdx.x, tid = threadIdx.x;
    {
        int t = tid >> 3, c0 = (tid & 7) * 8;
        const float* src = &g[((size_t)t*2048 + bn)*64 + c0];
        float f8[8];
        *(float4*)f8 = *(const float4*)src;
        *(float4*)(f8+4) = *(const float4*)(src+4);
        uint4 hi, lo; split8(f8, hi, lo);
        int uu = (tid & 7) ^ (t & 7);
        *(uint4*)&sh[t][uu*8] = hi;
        *(uint4*)&sl[t][uu*8] = lo;
    }
    __syncthreads();
    int w = tid >> 6, l = tid & 63, lm = l & 15, ld = l >> 4;
    int co = w*16 + lm;
    f32x4 acc0 = {0.f,0.f,0.f,0.f}, acc1 = {0.f,0.f,0.f,0.f};
    const s16x8 zf = {0,0,0,0,0,0,0,0};
    for (int kc = 0; kc < K32; ++kc) {
        int ka = kc >> 1;
        int ci = (kc & 1)*32 + ld*8;
        s16x8 yh = *(const s16x8*)&wch[(size_t)co*K + kc*32 + ld*8];
        s16x8 yl = *(const s16x8*)&wcl[(size_t)co*K + kc*32 + ld*8];
        #pragma unroll
        for (int Mt = 0; Mt < 2; ++Mt) {
            int ts = Mt*16 + lm + ka - P;
            bool ok = ((unsigned)ts) < 32u;
            int tc = ok ? ts : 0;
            int ua = (ci >> 3) ^ (tc & 7);
            s16x8 xh = *(const s16x8*)&sh[tc][ua*8];
            s16x8 xl = *(const s16x8*)&sl[tc][ua*8];
            if (!ok) { xh = zf; xl = zf; }
            f32x4& a = Mt ? acc1 : acc0;
            a = __builtin_amdgcn_mfma_f32_16x16x32_bf16(xh, yh, a, 0, 0, 0);
            a = __builtin_amdgcn_mfma_f32_16x16x32_bf16(xh, yl, a, 0, 0, 0);
            a = __builtin_amdgcn_mfma_f32_16x16x32_bf16(xl, yh, a, 0, 0, 0);
        }
    }
    float bias = cb[co];
    if (LAST) {
        int b = bn >> 6, n = bn & 63;
        ush* ob = fo + (size_t)b*KFLAT + n*2048 + co*32;
        #pragma unroll
        for (int Mt = 0; Mt < 2; ++Mt) {
            const f32x4& a = Mt ? acc1 : acc0;
            ush hv[4];
            #pragma unroll
            for (int r = 0; r < 4; ++r) {
                float val = a[r] + bias;
                val = (val >= 0.f) ? val : 0.01f*val;
                hv[r] = f2bf(val);
            }
            *(uint2*)&ob[Mt*16 + ld*4] = make_uint2(hv[0]|(hv[1]<<16), hv[2]|(hv[3]<<16));
        }
    } else {
        #pragma unroll
        for (int Mt = 0; Mt < 2; ++Mt) {
            const f32x4& a = Mt ? acc1 : acc0;
            #pragma unroll
            for (int r = 0; r < 4; ++r) {
                int t = Mt*16 + ld*4 + r;
                float val = a[r] + bias;
                val = (val >= 0.f) ? val : 0.01f*val;
                g[((size_t)t*2048 + bn)*64 + co] = val;
            }
        }
    }
}

// ---------------- final GEMM v4: W direct-to-register, A via LDS -----------
// Each W row is consumed by exactly one wave -> stream W to registers with a
// 3-deep pipeline; only the shared A tile (4 KB) goes through LDS (4-deep,
// global_load_lds). One barrier per step; counted vmcnt(10).
__global__ __launch_bounds__(256) void gemm_mfma(const ush* __restrict__ flat,
                                                 const float* __restrict__ W,
                                                 float* __restrict__ out)
{
    __shared__ __align__(16) ush Al[4][32][64];   // 16 KB
    const int tid = threadIdx.x;
    const int w = tid >> 6, l = tid & 63;
    const int og = blockIdx.x >> 6;
    const int kc = blockIdx.x & 63;
    const int o_blk = og * 64;
    const int kbase = kc * 2048;
    const int lmod = l & 15, ldiv = l >> 4, lx = l & 7;

    // A staging (per wave one gl2lds: rows w*8..w*8+7), pre-swizzled source
    const int arow = w*8 + (l >> 3);
    const int au = l & 7;
    const ush* aptr = flat + (size_t)arow*KFLAT + (unsigned)((au ^ (arow & 7))*8) + kbase;
    // W per-lane register stream: row o_blk + w*16 + lmod, k base + ldiv*8
    const float* wptr = W + (size_t)(o_blk + w*16 + lmod)*KFLAT + kbase + ldiv*8;

    float4 wr0[4], wr1[4], wr2[4];
#define LOADW(dst_, s_) { \
    dst_[0] = *(const float4*)(wptr + (s_)*64);      \
    dst_[1] = *(const float4*)(wptr + (s_)*64 + 4);  \
    dst_[2] = *(const float4*)(wptr + (s_)*64 + 32); \
    dst_[3] = *(const float4*)(wptr + (s_)*64 + 36); }
#define ISSUEA(s_) gl2lds16(aptr + (s_)*64, &Al[(s_)&3][w*8][0]);

    f32x4 acc0 = {0.f,0.f,0.f,0.f}, acc1 = {0.f,0.f,0.f,0.f};

#define COMPUTE(wr_, s_) { \
    const int abuf_ = (s_) & 3; \
    _Pragma("unroll") \
    for (int ksub = 0; ksub < 2; ++ksub) { \
        float bf_[8] = {wr_[ksub*2].x, wr_[ksub*2].y, wr_[ksub*2].z, wr_[ksub*2].w, \
                        wr_[ksub*2+1].x, wr_[ksub*2+1].y, wr_[ksub*2+1].z, wr_[ksub*2+1].w}; \
        s16x8 bhi_; \
        _Pragma("unroll") \
        for (int i_ = 0; i_ < 8; ++i_) bhi_[i_] = (short)f2bf(bf_[i_]); \
        int jua_ = ksub*4 + ldiv; \
        const s16x8 a0_ = *(const s16x8*)&Al[abuf_][lmod]     [(jua_ ^ lx)*8]; \
        const s16x8 a1_ = *(const s16x8*)&Al[abuf_][16 + lmod][(jua_ ^ lx)*8]; \
        acc0 = __builtin_amdgcn_mfma_f32_16x16x32_bf16(a0_, bhi_, acc0, 0, 0, 0); \
        acc1 = __builtin_amdgcn_mfma_f32_16x16x32_bf16(a1_, bhi_, acc1, 0, 0, 0); \
    } }

    LOADW(wr0, 0); ISSUEA(0);
    LOADW(wr1, 1); ISSUEA(1);
    LOADW(wr2, 2); ISSUEA(2);

    for (int s = 0; s < 30; s += 3) {
        asm volatile("s_waitcnt vmcnt(10)" ::: "memory");
        __builtin_amdgcn_s_barrier();
        COMPUTE(wr0, s);
        if (s + 3 < 32) { LOADW(wr0, s+3); ISSUEA(s+3); }
        asm volatile("s_waitcnt vmcnt(10)" ::: "memory");
        __builtin_amdgcn_s_barrier();
        COMPUTE(wr1, s+1);
        if (s + 4 < 32) { LOADW(wr1, s+4); ISSUEA(s+4); }
        asm volatile("s_waitcnt vmcnt(10)" ::: "memory");
        __builtin_amdgcn_s_barrier();
        COMPUTE(wr2, s+2);
        if (s + 5 < 32) { LOADW(wr2, s+5); ISSUEA(s+5); }
    }
    asm volatile("s_waitcnt vmcnt(5)" ::: "memory");
    __builtin_amdgcn_s_barrier();
    COMPUTE(wr0, 30);
    asm volatile("s_waitcnt vmcnt(0)" ::: "memory");
    __builtin_amdgcn_s_barrier();
    COMPUTE(wr1, 31);
#undef LOADW
#undef ISSUEA
#undef COMPUTE

    const int o_out = o_blk + w*16 + lmod;
    #pragma unroll
    for (int r = 0; r < 4; ++r) {
        int b0_ = ldiv*4 + r;
        atomicAdd(&out[(size_t)b0_*OUTD + o_out], acc0[r]);
        atomicAdd(&out[(size_t)(16 + b0_)*OUTD + o_out], acc1[r]);
    }
}

extern "C" void kernel_launch(void* const* d_in, const int* in_sizes, int n_in,
                              void* d_out, int out_size, void* d_ws, size_t ws_size,
                              hipStream_t stream) {
    (void)in_sizes; (void)n_in; (void)out_size; (void)ws_size;
    const float* x        = (const float*)d_in[0];
    const float* w_x2i    = (const float*)d_in[1];
    const float* b_x2i    = (const float*)d_in[2];
    const float* gru_wih  = (const float*)d_in[3];
    const float* gru_whh  = (const float*)d_in[4];
    const float* gru_bih  = (const float*)d_in[5];
    const float* gru_bhh  = (const float*)d_in[6];
    const float* wq_w     = (const float*)d_in[7];
    const float* wq_b     = (const float*)d_in[8];
    const float* wk_w     = (const float*)d_in[9];
    const float* wk_b     = (const float*)d_in[10];
    const float* gcn_w[3]  = {(const float*)d_in[11], (const float*)d_in[15], (const float*)d_in[19]};
    const float* gcn_b[3]  = {(const float*)d_in[12], (const float*)d_in[16], (const float*)d_in[20]};
    const float* conv_w[3] = {(const float*)d_in[13], (const float*)d_in[17], (const float*)d_in[21]};
    const float* conv_b[3] = {(const float*)d_in[14], (const float*)d_in[18], (const float*)d_in[22]};
    const float* lout_w   = (const float*)d_in[23];
    const float* lout_b   = (const float*)d_in[24];
    float* out = (float*)d_out;
    float* ws  = (float*)d_ws;

    float* hT   = ws;                        // 131072
    float* u    = ws + 131072;               // 2048
    float* v    = ws + 133120;               // 2048
    float* bufA = ws + 135168;               // 4194304
    float* bufB = bufA + 4194304;            // 4194304  (ends 8523776 floats)
    ush* usb = (ush*)(ws + 8523776);
    ush* whT_hi  = usb;                      // 131072
    ush* whT_lo  = usb + 131072;
    ush* gwT1_hi = usb + 262144;
    ush* gwT1_lo = usb + 393216;
    ush* gwT2_hi = usb + 524288;
    ush* gwT2_lo = usb + 655360;
    ush* cw2_hi  = usb + 786432;             // 20480
    ush* cw2_lo  = usb + 806912;
    ush* cw3_hi  = usb + 827392;             // 28672
    ush* cw3_lo  = usb + 856064;             // ends 884736 ush = 442368 floats
    float* fxtra = ws + 8523776 + 442368;    // float region
    float* sbuf  = fxtra;                    // 65536
    float* dgbuf = fxtra + 65536;            // 2048
    float* Au    = fxtra + 67584;            // 6144
    float* Av    = fxtra + 73728;            // 6144
    float* Ag    = fxtra + 79872;            // 6144

    prep_gru_kernel<<<dim3(512), dim3(256), 0, stream>>>(
        x, gru_wih, gru_whh, gru_bih, gru_bhh, hT,
        gcn_w[0], w_x2i, b_x2i, u, v,
        gcn_w[1], gwT1_hi, gwT1_lo,
        gcn_w[2], gwT2_hi, gwT2_lo,
        conv_w[1], cw2_hi, cw2_lo,
        conv_w[2], cw3_hi, cw3_lo,
        lout_b, out);
    attn_kernel<<<dim3(33), dim3(256), 0, stream>>>(
        hT, wq_w, wq_b, wk_w, wk_b, whT_hi, whT_lo,
        x, sbuf, dgbuf, u, v, conv_w[0], gcn_b[0], Au, Av, Ag);

    unsigned short* flat16 = (unsigned short*)bufB;
    fused1_kernel<<<dim3(2048), dim3(256), 0, stream>>>(sbuf, dgbuf, Au, Av, Ag,
                                                        conv_b[0], bufA);
    gcn_mfma<<<dim3(1024), dim3(256), 0, stream>>>(bufA, gwT1_hi, gwT1_lo,
                                                   whT_hi, whT_lo, gcn_b[1], bufB);
    conv_mfma<5,false><<<dim3(2048), dim3(256), 0, stream>>>(bufB, cw2_hi, cw2_lo, conv_b[1], nullptr);
    gcn_mfma<<<dim3(1024), dim3(256), 0, stream>>>(bufB, gwT2_hi, gwT2_lo,
                                                   whT_hi, whT_lo, gcn_b[2], bufA);
    conv_mfma<7,true><<<dim3(2048), dim3(256), 0, stream>>>(bufA, cw3_hi, cw3_lo, conv_b[2], flat16);

    gemm_mfma<<<dim3(768), dim3(256), 0, stream>>>(flat16, lout_w, out);
}

// Round 9
// 437.136 us; speedup vs baseline: 1.0099x; 1.0099x over previous
//
#include <hip/hip_runtime.h>
#include <hip/hip_bf16.h>

// Problem constants
#define BB 32   // batch
#define TT 32   // window
#define NN 64   // num_series
#define CC 64   // inter_dim
#define HH 64   // gru hidden
#define QKD 32  // qk dim
#define HOR 12
#define OUTD (NN*HOR)        // 768
#define KFLAT (NN*CC*TT)     // 131072

typedef __attribute__((ext_vector_type(4))) float f32x4;
typedef __attribute__((ext_vector_type(8))) short s16x8;
typedef unsigned short ush;

static __device__ __forceinline__ ush f2bf(float f) {
    unsigned u = __float_as_uint(f);
    unsigned r = (u + 0x7FFFu + ((u >> 16) & 1u)) >> 16;
    return (ush)r;
}
static __device__ __forceinline__ float bf2f(ush h) {
    return __uint_as_float(((unsigned)h) << 16);
}
static __device__ __forceinline__ void split8(const float* f, uint4& hi, uint4& lo) {
    unsigned hh[8], ll[8];
    #pragma unroll
    for (int i = 0; i < 8; ++i) {
        ush h = f2bf(f[i]);
        float hf = bf2f(h);
        hh[i] = h;
        ll[i] = f2bf(f[i] - hf);
    }
    hi = make_uint4(hh[0] | (hh[1] << 16), hh[2] | (hh[3] << 16),
                    hh[4] | (hh[5] << 16), hh[6] | (hh[7] << 16));
    lo = make_uint4(ll[0] | (ll[1] << 16), ll[2] | (ll[3] << 16),
                    ll[4] | (ll[5] << 16), ll[6] | (ll[7] << 16));
}
static __device__ __forceinline__ void gl2lds16(const void* gsrc, void* ldst) {
    __builtin_amdgcn_global_load_lds(
        (const __attribute__((address_space(1))) unsigned int*)gsrc,
        (__attribute__((address_space(3))) unsigned int*)ldst, 16, 0, 0);
}

// ---------------- prep (blocks<320) + GRU (all 512 blocks) -----------------
__global__ __launch_bounds__(256) void prep_gru_kernel(
    const float* __restrict__ x, const float* __restrict__ wih,
    const float* __restrict__ whh, const float* __restrict__ bih,
    const float* __restrict__ bhh, float* __restrict__ hT,
    const float* __restrict__ gw0, const float* __restrict__ wx, const float* __restrict__ bx,
    float* __restrict__ u, float* __restrict__ v,
    const float* __restrict__ gw1, ush* __restrict__ g1h, ush* __restrict__ g1l,
    const float* __restrict__ gw2, ush* __restrict__ g2h, ush* __restrict__ g2l,
    const float* __restrict__ cw2, ush* __restrict__ c2h, ush* __restrict__ c2l,
    const float* __restrict__ cw3, ush* __restrict__ c3h, ush* __restrict__ c3l,
    const float* __restrict__ lb, float* __restrict__ out)
{
    __shared__ __align__(16) char smem[17408];
    int bid = blockIdx.x, tid = threadIdx.x;

    // ---- phase A: prep ----
    if (bid < 32) {                       // u/v rank-1 prep, t=bid
        float (*pu)[64] = (float(*)[64])smem;
        float (*pv)[64] = (float(*)[64])(smem + 1024);
        int t = bid, d = tid & 63, cq = tid >> 6;
        float su = 0.f, sv = 0.f;
        for (int c = cq*16; c < cq*16 + 16; ++c) {
            float gv = gw0[t*4096 + c*64 + d];
            su += wx[c]*gv; sv += bx[c]*gv;
        }
        pu[cq][d] = su; pv[cq][d] = sv;
        __syncthreads();
        if (tid < 64) {
            u[t*64 + tid] = pu[0][tid]+pu[1][tid]+pu[2][tid]+pu[3][tid];
            v[t*64 + tid] = pv[0][tid]+pv[1][tid]+pv[2][tid]+pv[3][tid];
        }
    } else if (bid < 96) {                // gwT split
        const float* gw = (bid < 64) ? gw1 : gw2;
        ush* hi = (bid < 64) ? g1h : g2h;
        ush* lo = (bid < 64) ? g1l : g2l;
        int t = (bid < 64) ? bid - 32 : bid - 64;
        for (int idx = tid; idx < 4096; idx += 256) {
            int d = idx >> 6, c = idx & 63;
            float val = gw[t*4096 + c*64 + d];
            ush h = f2bf(val);
            hi[t*4096 + idx] = h;
            lo[t*4096 + idx] = f2bf(val - bf2f(h));
        }
    } else if (bid < 224) {               // conv weight split (cw2, cw3 only)
        const float* cw; ush *hi, *lo; int KW, co;
        if (bid < 160) { cw = cw2; hi = c2h; lo = c2l; KW = 5; co = bid - 96; }
        else           { cw = cw3; hi = c3h; lo = c3l; KW = 7; co = bid - 160; }
        int K = KW*64;
        for (int idx = tid; idx < K; idx += 256) {
            int ka = idx >> 6, ci = idx & 63;
            float val = cw[(size_t)(co*64 + ci)*KW + ka];
            ush h = f2bf(val);
            hi[(size_t)co*K + idx] = h;
            lo[(size_t)co*K + idx] = f2bf(val - bf2f(h));
        }
    } else if (bid < 320) {               // out init with bias (96 blocks)
        int idx = (bid - 224)*256 + tid;
        out[idx] = lb[idx % OUTD];
    }
    __syncthreads();

    // ---- phase B: GRU ----
    {
        float (*hbuf)[64] = (float(*)[64])smem;       // 1 KB
        float4* part = (float4*)(smem + 1024);        // 16 KB
        int w = tid >> 6, j = tid & 63;
        float Wreg[3][16];
        #pragma unroll
        for (int g = 0; g < 3; ++g)
            #pragma unroll
            for (int q = 0; q < 4; ++q) {
                float4 wv = *(const float4*)&whh[(g*64 + j)*64 + w*16 + q*4];
                Wreg[g][q*4+0] = wv.x; Wreg[g][q*4+1] = wv.y;
                Wreg[g][q*4+2] = wv.z; Wreg[g][q*4+3] = wv.w;
            }
        hbuf[w][j] = 0.0f;
        int gs0 = bid * 4;
        int b = gs0 >> 6, n0 = gs0 & 63;
        float wih_r = wih[j], wih_z = wih[64+j], wih_n = wih[128+j];
        float bi_r = bih[j], bi_z = bih[64+j], bi_n = bih[128+j];
        float bh_r = bhh[j], bh_z = bhh[64+j], bh_n = bhh[128+j];
        __syncthreads();
        float hreg = 0.0f;
        for (int t = 0; t < TT; ++t) {
            float p[3][4];
            #pragma unroll
            for (int g = 0; g < 3; ++g)
                #pragma unroll
                for (int s = 0; s < 4; ++s) p[g][s] = 0.f;
            #pragma unroll
            for (int s = 0; s < 4; ++s) {
                #pragma unroll
                for (int q = 0; q < 4; ++q) {
                    const float4 hv = *(const float4*)&hbuf[s][w*16 + q*4];
                    #pragma unroll
                    for (int g = 0; g < 3; ++g) {
                        p[g][s] += hv.x*Wreg[g][q*4]   + hv.y*Wreg[g][q*4+1]
                                 + hv.z*Wreg[g][q*4+2] + hv.w*Wreg[g][q*4+3];
                    }
                }
            }
            #pragma unroll
            for (int s = 0; s < 4; ++s)
                part[(w*4 + s)*64 + j] = make_float4(p[0][s], p[1][s], p[2][s], 0.f);
            __syncthreads();
            float4 q0 = part[(0*4 + w)*64 + j];
            float4 q1 = part[(1*4 + w)*64 + j];
            float4 q2 = part[(2*4 + w)*64 + j];
            float4 q3 = part[(3*4 + w)*64 + j];
            float gr = bh_r + q0.x + q1.x + q2.x + q3.x;
            float gz = bh_z + q0.y + q1.y + q2.y + q3.y;
            float gn = bh_n + q0.z + q1.z + q2.z + q3.z;
            float xt = x[(b*TT + t)*NN + n0 + w];
            float r = 1.f/(1.f+__expf(-(xt*wih_r + bi_r + gr)));
            float z = 1.f/(1.f+__expf(-(xt*wih_z + bi_z + gz)));
            float nn_ = tanhf(xt*wih_n + bi_n + r*gn);
            float hnew = (1.f - z)*nn_ + z*hreg;
            hreg = hnew;
            hbuf[w][j] = hnew;
            __syncthreads();
        }
        hT[(gs0 + w)*64 + j] = hreg;
    }
}

// ---------------- attention + s/dg + stage1 tables -------------------------
__global__ __launch_bounds__(256) void attn_kernel(
    const float* __restrict__ hT, const float* __restrict__ wq_w,
    const float* __restrict__ wq_b, const float* __restrict__ wk_w,
    const float* __restrict__ wk_b,
    ush* __restrict__ whT_hi, ush* __restrict__ whT_lo,
    const float* __restrict__ x, float* __restrict__ sbuf, float* __restrict__ dgbuf,
    const float* __restrict__ u, const float* __restrict__ v,
    const float* __restrict__ cw1, const float* __restrict__ gb0,
    float* __restrict__ Au, float* __restrict__ Av, float* __restrict__ Ag)
{
    int b = blockIdx.x, tid = threadIdx.x;
    if (b == 32) {   // tables: A*[ka][t][co] = sum_ci cw1[co][ci][ka] * {u,v,gb0}[t][ci]
        for (int idx = tid; idx < 3*32*64; idx += 256) {
            int ka = idx >> 11;
            int t  = (idx >> 6) & 31;
            int co = idx & 63;
            float au_ = 0.f, av_ = 0.f, ag_ = 0.f;
            for (int ci = 0; ci < 64; ++ci) {
                float w_ = cw1[(size_t)(co*64 + ci)*3 + ka];
                au_ += w_ * u[t*64 + ci];
                av_ += w_ * v[t*64 + ci];
                ag_ += w_ * gb0[t*64 + ci];
            }
            Au[idx] = au_; Av[idx] = av_; Ag[idx] = ag_;
        }
        return;
    }
    __shared__ float hs[64][64];                 // reused as xl[32][64] later
    __shared__ float Qs[64][33], Ks[64][33];
    __shared__ float S[64][65];
    __shared__ float pd[4][64];
    __shared__ float dinv[64];
    float (*xl)[64] = (float(*)[64])hs;
    for (int idx = tid; idx < 64*64; idx += 256) hs[idx>>6][idx&63] = hT[b*4096 + idx];
    __syncthreads();
    for (int idx = tid; idx < 64*32; idx += 256) {
        int n_ = idx >> 5, q = idx & 31;
        float accq = wq_b[q], acck = wk_b[q];
        #pragma unroll 8
        for (int h_ = 0; h_ < 64; ++h_) {
            float hv = hs[n_][h_];
            accq += hv * wq_w[q*64 + h_];
            acck += hv * wk_w[q*64 + h_];
        }
        Qs[n_][q] = accq; Ks[n_][q] = acck;
    }
    __syncthreads();
    const float scale = 0.17677669529663687f; // 1/sqrt(32)
    for (int idx = tid; idx < 64*64; idx += 256) {
        int n_ = idx >> 6, m = idx & 63;
        float acc = 0.f;
        #pragma unroll 8
        for (int q = 0; q < 32; ++q) acc += Qs[n_][q]*Ks[m][q];
        S[n_][m] = acc * scale;
    }
    __syncthreads();
    // hs no longer needed -> load x tile into its space
    for (int idx = tid; idx < 32*64; idx += 256) {
        int t = idx >> 6, i = idx & 63;
        xl[t][i] = x[(b*TT + t)*NN + i];
    }
    {   // row softmax: 4 lanes per row
        int r = tid >> 2, q = tid & 3;
        float mx = -1e30f;
        #pragma unroll
        for (int m = 0; m < 16; ++m) mx = fmaxf(mx, S[r][q*16+m]);
        mx = fmaxf(mx, __shfl_xor(mx, 1));
        mx = fmaxf(mx, __shfl_xor(mx, 2));
        float sum = 0.f;
        float e[16];
        #pragma unroll
        for (int m = 0; m < 16; ++m) { e[m] = __expf(S[r][q*16+m]-mx); sum += e[m]; }
        sum += __shfl_xor(sum, 1);
        sum += __shfl_xor(sum, 2);
        float inv = 1.f/sum;
        #pragma unroll
        for (int m = 0; m < 16; ++m) S[r][q*16+m] = e[m]*inv;
    }
    __syncthreads();
    {   // column degree of softmax matrix
        int c = tid & 63, rq = tid >> 6;
        float d = 0.f;
        #pragma unroll
        for (int i = 0; i < 16; ++i) d += S[rq*16 + i][c];
        pd[rq][c] = d;
    }
    __syncthreads();
    if (tid < 64) {
        float d = pd[0][tid]+pd[1][tid]+pd[2][tid]+pd[3][tid];
        dinv[tid] = (d > 0.f) ? 1.0f/sqrtf(d) : 0.f;
    }
    __syncthreads();
    // R[i][j] = dinv[i]*S[i][j]  (in place)
    for (int idx = tid; idx < 64*64; idx += 256) {
        int i = idx >> 6, j = idx & 63;
        S[i][j] *= dinv[i];
    }
    __syncthreads();
    // whT[j][i] = R[i][j]*dinv[j]
    for (int idx = tid; idx < 64*64; idx += 256) {
        int jj = idx >> 6, ii = idx & 63;
        float val = S[ii][jj]*dinv[jj];
        ush h = f2bf(val);
        whT_hi[b*4096 + idx] = h;
        whT_lo[b*4096 + idx] = f2bf(val - bf2f(h));
    }
    // dg[j] = dinv[j] * sum_i R[i][j]
    {
        int c = tid & 63, rq = tid >> 6;
        float d = 0.f;
        #pragma unroll
        for (int i = 0; i < 16; ++i) d += S[rq*16 + i][c];
        pd[rq][c] = d;
    }
    __syncthreads();
    if (tid < 64) {
        dgbuf[b*64 + tid] = dinv[tid]*(pd[0][tid]+pd[1][tid]+pd[2][tid]+pd[3][tid]);
    }
    // s[b][t][j] = dinv[j] * sum_i R[i][j]*x[t][i]
    {
        int j = tid & 63, tq = tid >> 6;
        float acc[8];
        #pragma unroll
        for (int uu = 0; uu < 8; ++uu) acc[uu] = 0.f;
        for (int i = 0; i < 64; ++i) {
            float rv = S[i][j];
            #pragma unroll
            for (int uu = 0; uu < 8; ++uu)
                acc[uu] += rv * xl[tq*8 + uu][i];
        }
        float dj = dinv[j];
        #pragma unroll
        for (int uu = 0; uu < 8; ++uu)
            sbuf[(b*32 + tq*8 + uu)*64 + j] = acc[uu] * dj;
    }
}

// ---------------- collapsed stage 1: rank-1 gcn + conv1 + leaky ------------
__global__ __launch_bounds__(256) void fused1_kernel(
    const float* __restrict__ sbuf, const float* __restrict__ dgbuf,
    const float* __restrict__ Au, const float* __restrict__ Av, const float* __restrict__ Ag,
    const float* __restrict__ cb1, float* __restrict__ o)
{
    __shared__ float sl[32];
    __shared__ float dgl;
    int bn = blockIdx.x, b = bn >> 6, n = bn & 63;
    int tid = threadIdx.x;
    if (tid < 32) sl[tid] = sbuf[(b*32 + tid)*64 + n];
    if (tid == 32) dgl = dgbuf[b*64 + n];
    __syncthreads();
    int co = tid & 63, tg = tid >> 6;
    float cb = cb1[co];
    float d = dgl;
    #pragma unroll
    for (int uu = 0; uu < 8; ++uu) {
        int t = tg*8 + uu;
        float acc = cb;
        #pragma unroll
        for (int ka = 0; ka < 3; ++ka) {
            int tp = t + ka - 1;
            if (tp >= 0 && tp < 32) {
                int ti = (ka*32 + tp)*64 + co;
                acc += sl[tp]*Au[ti] + d*Av[ti] + Ag[ti];
            }
        }
        acc = (acc >= 0.f) ? acc : 0.01f*acc;
        o[((size_t)t*2048 + bn)*64 + co] = acc;
    }
}

// ---------------- GCN via MFMA (hi/lo split) -------------------------------
__global__ __launch_bounds__(256) void gcn_mfma(
    const float* __restrict__ fin,
    const ush* __restrict__ gwT_hi, const ush* __restrict__ gwT_lo,
    const ush* __restrict__ whT_hi, const ush* __restrict__ whT_lo,
    const float* __restrict__ gb, float* __restrict__ o)
{
    __shared__ __align__(16) ush ft_hi[64][64], ft_lo[64][64];
    __shared__ __align__(16) ush xsT_hi[64][64], xsT_lo[64][64];
    int tb = blockIdx.x, t = tb >> 5, b = tb & 31;
    int tid = threadIdx.x;
    int w = tid >> 6, l = tid & 63, lm = l & 15, ld = l >> 4;

    {
        int row = tid >> 2, c0 = (tid & 3) * 16;
        const float* src = fin + (size_t)tb*4096 + row*64 + c0;
        float f8a[8], f8b[8];
        *(float4*)f8a = *(const float4*)src;       *(float4*)(f8a+4) = *(const float4*)(src+4);
        *(float4*)f8b = *(const float4*)(src+8);   *(float4*)(f8b+4) = *(const float4*)(src+12);
        uint4 hi, lo;
        split8(f8a, hi, lo);
        int u0 = ((c0>>3)) ^ (row & 7);
        *(uint4*)&ft_hi[row][u0*8] = hi; *(uint4*)&ft_lo[row][u0*8] = lo;
        split8(f8b, hi, lo);
        int u1 = ((c0>>3)+1) ^ (row & 7);
        *(uint4*)&ft_hi[row][u1*8] = hi; *(uint4*)&ft_lo[row][u1*8] = lo;
    }
    __syncthreads();
    f32x4 acc[4];
    #pragma unroll
    for (int ct = 0; ct < 4; ++ct) acc[ct] = (f32x4){0.f,0.f,0.f,0.f};
    #pragma unroll
    for (int kc = 0; kc < 2; ++kc) {
        int nrow = w*16 + lm;
        int ux = (kc*4 + ld) ^ (nrow & 7);
        s16x8 xh = *(const s16x8*)&ft_hi[nrow][ux*8];
        s16x8 xl = *(const s16x8*)&ft_lo[nrow][ux*8];
        #pragma unroll
        for (int ct = 0; ct < 4; ++ct) {
            int drow = ct*16 + lm;
            s16x8 yh = *(const s16x8*)&gwT_hi[t*4096 + drow*64 + kc*32 + ld*8];
            s16x8 yl = *(const s16x8*)&gwT_lo[t*4096 + drow*64 + kc*32 + ld*8];
            acc[ct] = __builtin_amdgcn_mfma_f32_16x16x32_bf16(xh, yh, acc[ct], 0, 0, 0);
            acc[ct] = __builtin_amdgcn_mfma_f32_16x16x32_bf16(xh, yl, acc[ct], 0, 0, 0);
            acc[ct] = __builtin_amdgcn_mfma_f32_16x16x32_bf16(xl, yh, acc[ct], 0, 0, 0);
        }
    }
    #pragma unroll
    for (int ct = 0; ct < 4; ++ct) {
        int d = ct*16 + lm;
        int n0 = w*16 + ld*4;
        ush hh[4], llo[4];
        #pragma unroll
        for (int r = 0; r < 4; ++r) {
            float val = acc[ct][r];
            ush h = f2bf(val);
            hh[r] = h; llo[r] = f2bf(val - bf2f(h));
        }
        int un = (n0 >> 3) ^ (d & 7);
        int base = d*64 + un*8 + (n0 & 7);
        *(uint2*)&xsT_hi[0][0 + base] = make_uint2(hh[0]|(hh[1]<<16), hh[2]|(hh[3]<<16));
        *(uint2*)&xsT_lo[0][0 + base] = make_uint2(llo[0]|(llo[1]<<16), llo[2]|(llo[3]<<16));
    }
    __syncthreads();

    f32x4 acc2[4];
    #pragma unroll
    for (int ct = 0; ct < 4; ++ct) acc2[ct] = (f32x4){0.f,0.f,0.f,0.f};
    #pragma unroll
    for (int kc = 0; kc < 2; ++kc) {
        int jrow = w*16 + lm;
        s16x8 wh = *(const s16x8*)&whT_hi[b*4096 + jrow*64 + kc*32 + ld*8];
        s16x8 wl = *(const s16x8*)&whT_lo[b*4096 + jrow*64 + kc*32 + ld*8];
        #pragma unroll
        for (int ct = 0; ct < 4; ++ct) {
            int drow = ct*16 + lm;
            int uy = (kc*4 + ld) ^ (drow & 7);
            s16x8 yh = *(const s16x8*)&xsT_hi[drow][uy*8];
            s16x8 yl = *(const s16x8*)&xsT_lo[drow][uy*8];
            acc2[ct] = __builtin_amdgcn_mfma_f32_16x16x32_bf16(wh, yh, acc2[ct], 0, 0, 0);
            acc2[ct] = __builtin_amdgcn_mfma_f32_16x16x32_bf16(wh, yl, acc2[ct], 0, 0, 0);
            acc2[ct] = __builtin_amdgcn_mfma_f32_16x16x32_bf16(wl, yh, acc2[ct], 0, 0, 0);
        }
    }
    float* oo = o + (size_t)tb*4096;
    #pragma unroll
    for (int ct = 0; ct < 4; ++ct) {
        int d = ct*16 + lm;
        float bias = gb[t*64 + d];
        #pragma unroll
        for (int r = 0; r < 4; ++r) {
            int jj = w*16 + ld*4 + r;
            oo[jj*64 + d] = acc2[ct][r] + bias;
        }
    }
}

// ---------------- temporal conv1d via im2col MFMA + LeakyReLU --------------
template<int KW, bool LAST>
__global__ __launch_bounds__(256) void conv_mfma(float* __restrict__ g,
    const ush* __restrict__ wch, const ush* __restrict__ wcl,
    const float* __restrict__ cb, ush* __restrict__ fo)
{
    constexpr int P = KW/2, K = KW*64, K32 = KW*2;
    __shared__ __align__(16) ush sh[32][64], sl[32][64];
    int bn = blockIdx.x, tid = threadIdx.x;
    {
        int t = tid >> 3, c0 = (tid & 7) * 8;
        const float* src = &g[((size_t)t*2048 + bn)*64 + c0];
        float f8[8];
        *(float4*)f8 = *(const float4*)src;
        *(float4*)(f8+4) = *(const float4*)(src+4);
        uint4 hi, lo; split8(f8, hi, lo);
        int uu = (tid & 7) ^ (t & 7);
        *(uint4*)&sh[t][uu*8] = hi;
        *(uint4*)&sl[t][uu*8] = lo;
    }
    __syncthreads();
    int w = tid >> 6, l = tid & 63, lm = l & 15, ld = l >> 4;
    int co = w*16 + lm;
    f32x4 acc0 = {0.f,0.f,0.f,0.f}, acc1 = {0.f,0.f,0.f,0.f};
    const s16x8 zf = {0,0,0,0,0,0,0,0};
    for (int kc = 0; kc < K32; ++kc) {
        int ka = kc >> 1;
        int ci = (kc & 1)*32 + ld*8;
        s16x8 yh = *(const s16x8*)&wch[(size_t)co*K + kc*32 + ld*8];
        s16x8 yl = *(const s16x8*)&wcl[(size_t)co*K + kc*32 + ld*8];
        #pragma unroll
        for (int Mt = 0; Mt < 2; ++Mt) {
            int ts = Mt*16 + lm + ka - P;
            bool ok = ((unsigned)ts) < 32u;
            int tc = ok ? ts : 0;
            int ua = (ci >> 3) ^ (tc & 7);
            s16x8 xh = *(const s16x8*)&sh[tc][ua*8];
            s16x8 xl = *(const s16x8*)&sl[tc][ua*8];
            if (!ok) { xh = zf; xl = zf; }
            f32x4& a = Mt ? acc1 : acc0;
            a = __builtin_amdgcn_mfma_f32_16x16x32_bf16(xh, yh, a, 0, 0, 0);
            a = __builtin_amdgcn_mfma_f32_16x16x32_bf16(xh, yl, a, 0, 0, 0);
            a = __builtin_amdgcn_mfma_f32_16x16x32_bf16(xl, yh, a, 0, 0, 0);
        }
    }
    float bias = cb[co];
    if (LAST) {
        int b = bn >> 6, n = bn & 63;
        ush* ob = fo + (size_t)b*KFLAT + n*2048 + co*32;
        #pragma unroll
        for (int Mt = 0; Mt < 2; ++Mt) {
            const f32x4& a = Mt ? acc1 : acc0;
            ush hv[4];
            #pragma unroll
            for (int r = 0; r < 4; ++r) {
                float val = a[r] + bias;
                val = (val >= 0.f) ? val : 0.01f*val;
                hv[r] = f2bf(val);
            }
            *(uint2*)&ob[Mt*16 + ld*4] = make_uint2(hv[0]|(hv[1]<<16), hv[2]|(hv[3]<<16));
        }
    } else {
        #pragma unroll
        for (int Mt = 0; Mt < 2; ++Mt) {
            const f32x4& a = Mt ? acc1 : acc0;
            #pragma unroll
            for (int r = 0; r < 4; ++r) {
                int t = Mt*16 + ld*4 + r;
                float val = a[r] + bias;
                val = (val >= 0.f) ? val : 0.01f*val;
                g[((size_t)t*2048 + bn)*64 + co] = val;
            }
        }
    }
}

// ---------------- final GEMM via MFMA: async LDS staging, W-hi-only --------
// (round-7 version: coalesced global_load_lds staging, vmcnt(5) counted)
__global__ __launch_bounds__(256) void gemm_mfma(const ush* __restrict__ flat,
                                                 const float* __restrict__ W,
                                                 float* __restrict__ out)
{
    __shared__ __align__(16) float Wl[2][64][64];   // 32 KB
    __shared__ __align__(16) ush Al[2][32][64];     // 8 KB
    const int tid = threadIdx.x;
    const int w = tid >> 6, l = tid & 63;
    const int og = blockIdx.x >> 6;
    const int kc = blockIdx.x & 63;
    const int o_blk = og * 64;
    const int kbase = kc * 2048;

    const int wrow_l = l >> 4;
    const int wu = l & 15;
    size_t w_off[4];
    #pragma unroll
    for (int i = 0; i < 4; ++i) {
        int row = w*16 + i*4 + wrow_l;
        w_off[i] = (size_t)(o_blk + row) * KFLAT + (unsigned)((wu ^ (row & 7)) * 4);
    }
    const int arow = w*8 + (l >> 3);
    const int au = l & 7;
    const size_t a_off0 = (size_t)arow * KFLAT + (unsigned)((au ^ (arow & 7)) * 8);

#define ISSUE_TILE(buf_, s_) { \
    int kwin_ = kbase + (s_)*64; \
    _Pragma("unroll") \
    for (int i_ = 0; i_ < 4; ++i_) \
        gl2lds16(W + w_off[i_] + kwin_, &Wl[buf_][w*16 + i_*4][0]); \
    gl2lds16(flat + a_off0 + kwin_, &Al[buf_][w*8][0]); \
}

    f32x4 acc0 = {0.f,0.f,0.f,0.f}, acc1 = {0.f,0.f,0.f,0.f};
    ISSUE_TILE(0, 0);
    ISSUE_TILE(1, 1);

    const int lmod = l & 15, ldiv = l >> 4, lx = l & 7;
    for (int s = 0; s < 32; ++s) {
        if (s < 31) { asm volatile("s_waitcnt vmcnt(5)" ::: "memory"); }
        else        { asm volatile("s_waitcnt vmcnt(0)" ::: "memory"); }
        __builtin_amdgcn_s_barrier();
        asm volatile("" ::: "memory");
        const int cur = s & 1;
        #pragma unroll
        for (int ksub = 0; ksub < 2; ++ksub) {
            int ju = ksub*8 + ldiv*2;
            const float4 b0 = *(const float4*)&Wl[cur][w*16 + lmod][(ju ^ lx)*4];
            const float4 b1 = *(const float4*)&Wl[cur][w*16 + lmod][((ju+1) ^ lx)*4];
            float bf[8] = {b0.x,b0.y,b0.z,b0.w,b1.x,b1.y,b1.z,b1.w};
            s16x8 bhi;
            #pragma unroll
            for (int i = 0; i < 8; ++i) bhi[i] = (short)f2bf(bf[i]);
            int jua = ksub*4 + ldiv;
            const s16x8 a0 = *(const s16x8*)&Al[cur][lmod]      [(jua ^ lx)*8];
            const s16x8 a1 = *(const s16x8*)&Al[cur][16 + lmod] [(jua ^ lx)*8];
            acc0 = __builtin_amdgcn_mfma_f32_16x16x32_bf16(a0, bhi, acc0, 0, 0, 0);
            acc1 = __builtin_amdgcn_mfma_f32_16x16x32_bf16(a1, bhi, acc1, 0, 0, 0);
        }
        asm volatile("" ::: "memory");
        __builtin_amdgcn_s_barrier();
        if (s < 30) { ISSUE_TILE(cur, s+2); }
    }
#undef ISSUE_TILE

    const int o_out = o_blk + w*16 + lmod;
    #pragma unroll
    for (int r = 0; r < 4; ++r) {
        int b0_ = ldiv*4 + r;
        atomicAdd(&out[(size_t)b0_*OUTD + o_out], acc0[r]);
        atomicAdd(&out[(size_t)(16 + b0_)*OUTD + o_out], acc1[r]);
    }
}

extern "C" void kernel_launch(void* const* d_in, const int* in_sizes, int n_in,
                              void* d_out, int out_size, void* d_ws, size_t ws_size,
                              hipStream_t stream) {
    (void)in_sizes; (void)n_in; (void)out_size; (void)ws_size;
    const float* x        = (const float*)d_in[0];
    const float* w_x2i    = (const float*)d_in[1];
    const float* b_x2i    = (const float*)d_in[2];
    const float* gru_wih  = (const float*)d_in[3];
    const float* gru_whh  = (const float*)d_in[4];
    const float* gru_bih  = (const float*)d_in[5];
    const float* gru_bhh  = (const float*)d_in[6];
    const float* wq_w     = (const float*)d_in[7];
    const float* wq_b     = (const float*)d_in[8];
    const float* wk_w     = (const float*)d_in[9];
    const float* wk_b     = (const float*)d_in[10];
    const float* gcn_w[3]  = {(const float*)d_in[11], (const float*)d_in[15], (const float*)d_in[19]};
    const float* gcn_b[3]  = {(const float*)d_in[12], (const float*)d_in[16], (const float*)d_in[20]};
    const float* conv_w[3] = {(const float*)d_in[13], (const float*)d_in[17], (const float*)d_in[21]};
    const float* conv_b[3] = {(const float*)d_in[14], (const float*)d_in[18], (const float*)d_in[22]};
    const float* lout_w   = (const float*)d_in[23];
    const float* lout_b   = (const float*)d_in[24];
    float* out = (float*)d_out;
    float* ws  = (float*)d_ws;

    float* hT   = ws;                        // 131072
    float* u    = ws + 131072;               // 2048
    float* v    = ws + 133120;               // 2048
    float* bufA = ws + 135168;               // 4194304
    float* bufB = bufA + 4194304;            // 4194304  (ends 8523776 floats)
    ush* usb = (ush*)(ws + 8523776);
    ush* whT_hi  = usb;                      // 131072
    ush* whT_lo  = usb + 131072;
    ush* gwT1_hi = usb + 262144;
    ush* gwT1_lo = usb + 393216;
    ush* gwT2_hi = usb + 524288;
    ush* gwT2_lo = usb + 655360;
    ush* cw2_hi  = usb + 786432;             // 20480
    ush* cw2_lo  = usb + 806912;
    ush* cw3_hi  = usb + 827392;             // 28672
    ush* cw3_lo  = usb + 856064;             // ends 884736 ush = 442368 floats
    float* fxtra = ws + 8523776 + 442368;    // float region
    float* sbuf  = fxtra;                    // 65536
    float* dgbuf = fxtra + 65536;            // 2048
    float* Au    = fxtra + 67584;            // 6144
    float* Av    = fxtra + 73728;            // 6144
    float* Ag    = fxtra + 79872;            // 6144

    prep_gru_kernel<<<dim3(512), dim3(256), 0, stream>>>(
        x, gru_wih, gru_whh, gru_bih, gru_bhh, hT,
        gcn_w[0], w_x2i, b_x2i, u, v,
        gcn_w[1], gwT1_hi, gwT1_lo,
        gcn_w[2], gwT2_hi, gwT2_lo,
        conv_w[1], cw2_hi, cw2_lo,
        conv_w[2], cw3_hi, cw3_lo,
        lout_b, out);
    attn_kernel<<<dim3(33), dim3(256), 0, stream>>>(
        hT, wq_w, wq_b, wk_w, wk_b, whT_hi, whT_lo,
        x, sbuf, dgbuf, u, v, conv_w[0], gcn_b[0], Au, Av, Ag);

    unsigned short* flat16 = (unsigned short*)bufB;
    fused1_kernel<<<dim3(2048), dim3(256), 0, stream>>>(sbuf, dgbuf, Au, Av, Ag,
                                                        conv_b[0], bufA);
    gcn_mfma<<<dim3(1024), dim3(256), 0, stream>>>(bufA, gwT1_hi, gwT1_lo,
                                                   whT_hi, whT_lo, gcn_b[1], bufB);
    conv_mfma<5,false><<<dim3(2048), dim3(256), 0, stream>>>(bufB, cw2_hi, cw2_lo, conv_b[1], nullptr);
    gcn_mfma<<<dim3(1024), dim3(256), 0, stream>>>(bufB, gwT2_hi, gwT2_lo,
                                                   whT_hi, whT_lo, gcn_b[2], bufA);
    conv_mfma<7,true><<<dim3(2048), dim3(256), 0, stream>>>(bufA, cw3_hi, cw3_lo, conv_b[2], flat16);

    gemm_mfma<<<dim3(768), dim3(256), 0, stream>>>(flat16, lout_w, out);
}

// Round 10
// 303.986 us; speedup vs baseline: 1.4523x; 1.4380x over previous
//
#include <hip/hip_runtime.h>
#include <hip/hip_bf16.h>

// Problem constants
#define BB 32   // batch
#define TT 32   // window
#define NN 64   // num_series
#define CC 64   // inter_dim
#define HH 64   // gru hidden
#define QKD 32  // qk dim
#define HOR 12
#define OUTD (NN*HOR)        // 768
#define KFLAT (NN*CC*TT)     // 131072

typedef __attribute__((ext_vector_type(4))) float f32x4;
typedef __attribute__((ext_vector_type(8))) short s16x8;
typedef unsigned short ush;

static __device__ __forceinline__ ush f2bf(float f) {
    unsigned u = __float_as_uint(f);
    unsigned r = (u + 0x7FFFu + ((u >> 16) & 1u)) >> 16;
    return (ush)r;
}
static __device__ __forceinline__ float bf2f(ush h) {
    return __uint_as_float(((unsigned)h) << 16);
}
static __device__ __forceinline__ void split8(const float* f, uint4& hi, uint4& lo) {
    unsigned hh[8], ll[8];
    #pragma unroll
    for (int i = 0; i < 8; ++i) {
        ush h = f2bf(f[i]);
        float hf = bf2f(h);
        hh[i] = h;
        ll[i] = f2bf(f[i] - hf);
    }
    hi = make_uint4(hh[0] | (hh[1] << 16), hh[2] | (hh[3] << 16),
                    hh[4] | (hh[5] << 16), hh[6] | (hh[7] << 16));
    lo = make_uint4(ll[0] | (ll[1] << 16), ll[2] | (ll[3] << 16),
                    ll[4] | (ll[5] << 16), ll[6] | (ll[7] << 16));
}
static __device__ __forceinline__ void gl2lds16(const void* gsrc, void* ldst) {
    __builtin_amdgcn_global_load_lds(
        (const __attribute__((address_space(1))) unsigned int*)gsrc,
        (__attribute__((address_space(3))) unsigned int*)ldst, 16, 0, 0);
}

// ---------------- prep (blocks<384) + GRU (all 512 blocks) -----------------
// Prep outputs (u,v,gwT,cw splits, out-init) are consumed only by later
// kernels, and GRU state is block-local -> no barrier needed between phases.
__global__ __launch_bounds__(256) void prep_gru_kernel(
    const float* __restrict__ x, const float* __restrict__ wih,
    const float* __restrict__ whh, const float* __restrict__ bih,
    const float* __restrict__ bhh, float* __restrict__ hT,
    const float* __restrict__ gw0, const float* __restrict__ wx, const float* __restrict__ bx,
    float* __restrict__ u, float* __restrict__ v,
    const float* __restrict__ gw1, ush* __restrict__ g1h, ush* __restrict__ g1l,
    const float* __restrict__ gw2, ush* __restrict__ g2h, ush* __restrict__ g2l,
    const float* __restrict__ cw1, ush* __restrict__ c1h, ush* __restrict__ c1l,
    const float* __restrict__ cw2, ush* __restrict__ c2h, ush* __restrict__ c2l,
    const float* __restrict__ cw3, ush* __restrict__ c3h, ush* __restrict__ c3l,
    const float* __restrict__ lb, float* __restrict__ out)
{
    __shared__ __align__(16) char smem[17408];
    int bid = blockIdx.x, tid = threadIdx.x;

    // ---- phase A: prep ----
    if (bid < 32) {                       // u/v rank-1 prep, t=bid
        float (*pu)[64] = (float(*)[64])smem;
        float (*pv)[64] = (float(*)[64])(smem + 1024);
        int t = bid, d = tid & 63, cq = tid >> 6;
        float su = 0.f, sv = 0.f;
        for (int c = cq*16; c < cq*16 + 16; ++c) {
            float gv = gw0[t*4096 + c*64 + d];
            su += wx[c]*gv; sv += bx[c]*gv;
        }
        pu[cq][d] = su; pv[cq][d] = sv;
        __syncthreads();
        if (tid < 64) {
            u[t*64 + tid] = pu[0][tid]+pu[1][tid]+pu[2][tid]+pu[3][tid];
            v[t*64 + tid] = pv[0][tid]+pv[1][tid]+pv[2][tid]+pv[3][tid];
        }
    } else if (bid < 96) {                // gwT split
        const float* gw = (bid < 64) ? gw1 : gw2;
        ush* hi = (bid < 64) ? g1h : g2h;
        ush* lo = (bid < 64) ? g1l : g2l;
        int t = (bid < 64) ? bid - 32 : bid - 64;
        for (int idx = tid; idx < 4096; idx += 256) {
            int d = idx >> 6, c = idx & 63;
            float val = gw[t*4096 + c*64 + d];
            ush h = f2bf(val);
            hi[t*4096 + idx] = h;
            lo[t*4096 + idx] = f2bf(val - bf2f(h));
        }
    } else if (bid < 224) {               // conv weight split (cw2, cw3 only)
        const float* cw; ush *hi, *lo; int KW, co;
        if (bid < 160) { cw = cw2; hi = c2h; lo = c2l; KW = 5; co = bid - 96; }
        else           { cw = cw3; hi = c3h; lo = c3l; KW = 7; co = bid - 160; }
        int K = KW*64;
        for (int idx = tid; idx < K; idx += 256) {
            int ka = idx >> 6, ci = idx & 63;
            float val = cw[(size_t)(co*64 + ci)*KW + ka];
            ush h = f2bf(val);
            hi[(size_t)co*K + idx] = h;
            lo[(size_t)co*K + idx] = f2bf(val - bf2f(h));
        }
    } else if (bid < 288) {               // conv weight split (cw1)
        const float* cw = cw1; ush *hi = c1h, *lo = c1l; int KW = 3, co = bid - 224;
        int K = KW*64;
        for (int idx = tid; idx < K; idx += 256) {
            int ka = idx >> 6, ci = idx & 63;
            float val = cw[(size_t)(co*64 + ci)*KW + ka];
            ush h = f2bf(val);
            hi[(size_t)co*K + idx] = h;
            lo[(size_t)co*K + idx] = f2bf(val - bf2f(h));
        }
    } else if (bid < 384) {               // out init with bias (96 blocks)
        int idx = (bid - 288)*256 + tid;
        out[idx] = lb[idx % OUTD];
    }
    __syncthreads();

    // ---- phase B: GRU ----
    {
        float (*hbuf)[64] = (float(*)[64])smem;       // 1 KB
        float4* part = (float4*)(smem + 1024);        // 16 KB
        int w = tid >> 6, j = tid & 63;
        float Wreg[3][16];
        #pragma unroll
        for (int g = 0; g < 3; ++g)
            #pragma unroll
            for (int q = 0; q < 4; ++q) {
                float4 wv = *(const float4*)&whh[(g*64 + j)*64 + w*16 + q*4];
                Wreg[g][q*4+0] = wv.x; Wreg[g][q*4+1] = wv.y;
                Wreg[g][q*4+2] = wv.z; Wreg[g][q*4+3] = wv.w;
            }
        hbuf[w][j] = 0.0f;
        int gs0 = bid * 4;
        int b = gs0 >> 6, n0 = gs0 & 63;
        float wih_r = wih[j], wih_z = wih[64+j], wih_n = wih[128+j];
        float bi_r = bih[j], bi_z = bih[64+j], bi_n = bih[128+j];
        float bh_r = bhh[j], bh_z = bhh[64+j], bh_n = bhh[128+j];
        __syncthreads();
        float hreg = 0.0f;
        for (int t = 0; t < TT; ++t) {
            float p[3][4];
            #pragma unroll
            for (int g = 0; g < 3; ++g)
                #pragma unroll
                for (int s = 0; s < 4; ++s) p[g][s] = 0.f;
            #pragma unroll
            for (int s = 0; s < 4; ++s) {
                #pragma unroll
                for (int q = 0; q < 4; ++q) {
                    const float4 hv = *(const float4*)&hbuf[s][w*16 + q*4];
                    #pragma unroll
                    for (int g = 0; g < 3; ++g) {
                        p[g][s] += hv.x*Wreg[g][q*4]   + hv.y*Wreg[g][q*4+1]
                                 + hv.z*Wreg[g][q*4+2] + hv.w*Wreg[g][q*4+3];
                    }
                }
            }
            #pragma unroll
            for (int s = 0; s < 4; ++s)
                part[(w*4 + s)*64 + j] = make_float4(p[0][s], p[1][s], p[2][s], 0.f);
            __syncthreads();
            float4 q0 = part[(0*4 + w)*64 + j];
            float4 q1 = part[(1*4 + w)*64 + j];
            float4 q2 = part[(2*4 + w)*64 + j];
            float4 q3 = part[(3*4 + w)*64 + j];
            float gr = bh_r + q0.x + q1.x + q2.x + q3.x;
            float gz = bh_z + q0.y + q1.y + q2.y + q3.y;
            float gn = bh_n + q0.z + q1.z + q2.z + q3.z;
            float xt = x[(b*TT + t)*NN + n0 + w];
            float r = 1.f/(1.f+__expf(-(xt*wih_r + bi_r + gr)));
            float z = 1.f/(1.f+__expf(-(xt*wih_z + bi_z + gz)));
            float nn_ = tanhf(xt*wih_n + bi_n + r*gn);
            float hnew = (1.f - z)*nn_ + z*hreg;
            hreg = hnew;
            hbuf[w][j] = hnew;
            __syncthreads();
        }
        hT[(gs0 + w)*64 + j] = hreg;
    }
}

// ---------------- attention -> WhatT hi/lo bf16 (per batch) ----------------
__global__ __launch_bounds__(256) void attn_kernel(
    const float* __restrict__ hT, const float* __restrict__ wq_w,
    const float* __restrict__ wq_b, const float* __restrict__ wk_w,
    const float* __restrict__ wk_b,
    ush* __restrict__ whT_hi, ush* __restrict__ whT_lo)
{
    __shared__ float hs[64][64];
    __shared__ float Qs[64][33], Ks[64][33];
    __shared__ float S[64][65];
    __shared__ float pd[4][64];
    __shared__ float dinv[64];
    int b = blockIdx.x, tid = threadIdx.x;
    for (int idx = tid; idx < 64*64; idx += 256) hs[idx>>6][idx&63] = hT[b*4096 + idx];
    __syncthreads();
    for (int idx = tid; idx < 64*32; idx += 256) {
        int n_ = idx >> 5, q = idx & 31;
        float accq = wq_b[q], acck = wk_b[q];
        #pragma unroll 8
        for (int h_ = 0; h_ < 64; ++h_) {
            float hv = hs[n_][h_];
            accq += hv * wq_w[q*64 + h_];
            acck += hv * wk_w[q*64 + h_];
        }
        Qs[n_][q] = accq; Ks[n_][q] = acck;
    }
    __syncthreads();
    const float scale = 0.17677669529663687f; // 1/sqrt(32)
    for (int idx = tid; idx < 64*64; idx += 256) {
        int n_ = idx >> 6, m = idx & 63;
        float acc = 0.f;
        #pragma unroll 8
        for (int q = 0; q < 32; ++q) acc += Qs[n_][q]*Ks[m][q];
        S[n_][m] = acc * scale;
    }
    __syncthreads();
    {   // row softmax: 4 lanes per row
        int r = tid >> 2, q = tid & 3;
        float mx = -1e30f;
        #pragma unroll
        for (int m = 0; m < 16; ++m) mx = fmaxf(mx, S[r][q*16+m]);
        mx = fmaxf(mx, __shfl_xor(mx, 1));
        mx = fmaxf(mx, __shfl_xor(mx, 2));
        float sum = 0.f;
        float e[16];
        #pragma unroll
        for (int m = 0; m < 16; ++m) { e[m] = __expf(S[r][q*16+m]-mx); sum += e[m]; }
        sum += __shfl_xor(sum, 1);
        sum += __shfl_xor(sum, 2);
        float inv = 1.f/sum;
        #pragma unroll
        for (int m = 0; m < 16; ++m) S[r][q*16+m] = e[m]*inv;
    }
    __syncthreads();
    {   // column degree
        int c = tid & 63, rq = tid >> 6;
        float d = 0.f;
        #pragma unroll
        for (int i = 0; i < 16; ++i) d += S[rq*16 + i][c];
        pd[rq][c] = d;
    }
    __syncthreads();
    if (tid < 64) {
        float d = pd[0][tid]+pd[1][tid]+pd[2][tid]+pd[3][tid];
        dinv[tid] = (d > 0.f) ? 1.0f/sqrtf(d) : 0.f;
    }
    __syncthreads();
    for (int idx = tid; idx < 64*64; idx += 256) {
        int jj = idx >> 6, ii = idx & 63;
        float val = dinv[ii]*S[ii][jj]*dinv[jj];
        ush h = f2bf(val);
        whT_hi[b*4096 + idx] = h;
        whT_lo[b*4096 + idx] = f2bf(val - bf2f(h));
    }
}

// ---------------- GCN via MFMA (hi/lo split, fp32-class precision) ---------
template<bool FIRST>
__global__ __launch_bounds__(256) void gcn_mfma(
    const float* __restrict__ fin,
    const ush* __restrict__ gwT_hi, const ush* __restrict__ gwT_lo,
    const float* __restrict__ u, const float* __restrict__ v,
    const ush* __restrict__ whT_hi, const ush* __restrict__ whT_lo,
    const float* __restrict__ gb, float* __restrict__ o)
{
    __shared__ __align__(16) ush ft_hi[64][64], ft_lo[64][64];
    __shared__ __align__(16) ush xsT_hi[64][64], xsT_lo[64][64];
    __shared__ float x_l[64];
    int tb = blockIdx.x, t = tb >> 5, b = tb & 31;
    int tid = threadIdx.x;
    int w = tid >> 6, l = tid & 63, lm = l & 15, ld = l >> 4;

    if (FIRST) {
        if (tid < 64) x_l[tid] = fin[(b*TT + t)*NN + tid];
        __syncthreads();
        int d = tid >> 2, nq = tid & 3;
        float ud = u[t*64 + d], vd = v[t*64 + d];
        float vals[16];
        #pragma unroll
        for (int i = 0; i < 16; ++i) vals[i] = x_l[nq*16 + i]*ud + vd;
        #pragma unroll
        for (int h = 0; h < 2; ++h) {
            uint4 hi, lo; split8(&vals[h*8], hi, lo);
            int un = (nq*2 + h) ^ (d & 7);
            *(uint4*)&xsT_hi[d][un*8] = hi;
            *(uint4*)&xsT_lo[d][un*8] = lo;
        }
        __syncthreads();
    } else {
        {
            int row = tid >> 2, c0 = (tid & 3) * 16;
            const float* src = fin + (size_t)tb*4096 + row*64 + c0;
            float f8a[8], f8b[8];
            *(float4*)f8a = *(const float4*)src;       *(float4*)(f8a+4) = *(const float4*)(src+4);
            *(float4*)f8b = *(const float4*)(src+8);   *(float4*)(f8b+4) = *(const float4*)(src+12);
            uint4 hi, lo;
            split8(f8a, hi, lo);
            int u0 = ((c0>>3)) ^ (row & 7);
            *(uint4*)&ft_hi[row][u0*8] = hi; *(uint4*)&ft_lo[row][u0*8] = lo;
            split8(f8b, hi, lo);
            int u1 = ((c0>>3)+1) ^ (row & 7);
            *(uint4*)&ft_hi[row][u1*8] = hi; *(uint4*)&ft_lo[row][u1*8] = lo;
        }
        __syncthreads();
        f32x4 acc[4];
        #pragma unroll
        for (int ct = 0; ct < 4; ++ct) acc[ct] = (f32x4){0.f,0.f,0.f,0.f};
        #pragma unroll
        for (int kc = 0; kc < 2; ++kc) {
            int nrow = w*16 + lm;
            int ux = (kc*4 + ld) ^ (nrow & 7);
            s16x8 xh = *(const s16x8*)&ft_hi[nrow][ux*8];
            s16x8 xl = *(const s16x8*)&ft_lo[nrow][ux*8];
            #pragma unroll
            for (int ct = 0; ct < 4; ++ct) {
                int drow = ct*16 + lm;
                s16x8 yh = *(const s16x8*)&gwT_hi[t*4096 + drow*64 + kc*32 + ld*8];
                s16x8 yl = *(const s16x8*)&gwT_lo[t*4096 + drow*64 + kc*32 + ld*8];
                acc[ct] = __builtin_amdgcn_mfma_f32_16x16x32_bf16(xh, yh, acc[ct], 0, 0, 0);
                acc[ct] = __builtin_amdgcn_mfma_f32_16x16x32_bf16(xh, yl, acc[ct], 0, 0, 0);
                acc[ct] = __builtin_amdgcn_mfma_f32_16x16x32_bf16(xl, yh, acc[ct], 0, 0, 0);
            }
        }
        #pragma unroll
        for (int ct = 0; ct < 4; ++ct) {
            int d = ct*16 + lm;
            int n0 = w*16 + ld*4;
            ush hh[4], llo[4];
            #pragma unroll
            for (int r = 0; r < 4; ++r) {
                float val = acc[ct][r];
                ush h = f2bf(val);
                hh[r] = h; llo[r] = f2bf(val - bf2f(h));
            }
            int un = (n0 >> 3) ^ (d & 7);
            int base = d*64 + un*8 + (n0 & 7);
            *(uint2*)&xsT_hi[0][0 + base] = make_uint2(hh[0]|(hh[1]<<16), hh[2]|(hh[3]<<16));
            *(uint2*)&xsT_lo[0][0 + base] = make_uint2(llo[0]|(llo[1]<<16), llo[2]|(llo[3]<<16));
        }
        __syncthreads();
    }

    f32x4 acc2[4];
    #pragma unroll
    for (int ct = 0; ct < 4; ++ct) acc2[ct] = (f32x4){0.f,0.f,0.f,0.f};
    #pragma unroll
    for (int kc = 0; kc < 2; ++kc) {
        int jrow = w*16 + lm;
        s16x8 wh = *(const s16x8*)&whT_hi[b*4096 + jrow*64 + kc*32 + ld*8];
        s16x8 wl = *(const s16x8*)&whT_lo[b*4096 + jrow*64 + kc*32 + ld*8];
        #pragma unroll
        for (int ct = 0; ct < 4; ++ct) {
            int drow = ct*16 + lm;
            int uy = (kc*4 + ld) ^ (drow & 7);
            s16x8 yh = *(const s16x8*)&xsT_hi[drow][uy*8];
            s16x8 yl = *(const s16x8*)&xsT_lo[drow][uy*8];
            acc2[ct] = __builtin_amdgcn_mfma_f32_16x16x32_bf16(wh, yh, acc2[ct], 0, 0, 0);
            acc2[ct] = __builtin_amdgcn_mfma_f32_16x16x32_bf16(wh, yl, acc2[ct], 0, 0, 0);
            acc2[ct] = __builtin_amdgcn_mfma_f32_16x16x32_bf16(wl, yh, acc2[ct], 0, 0, 0);
        }
    }
    float* oo = o + (size_t)tb*4096;
    #pragma unroll
    for (int ct = 0; ct < 4; ++ct) {
        int d = ct*16 + lm;
        float bias = gb[t*64 + d];
        #pragma unroll
        for (int r = 0; r < 4; ++r) {
            int jj = w*16 + ld*4 + r;
            oo[jj*64 + d] = acc2[ct][r] + bias;
        }
    }
}

// ---------------- temporal conv1d via im2col MFMA + LeakyReLU --------------
template<int KW, bool LAST>
__global__ __launch_bounds__(256) void conv_mfma(float* __restrict__ g,
    const ush* __restrict__ wch, const ush* __restrict__ wcl,
    const float* __restrict__ cb, ush* __restrict__ fo)
{
    constexpr int P = KW/2, K = KW*64, K32 = KW*2;
    __shared__ __align__(16) ush sh[32][64], sl[32][64];
    int bn = blockIdx.x, tid = threadIdx.x;
    {
        int t = tid >> 3, c0 = (tid & 7) * 8;
        const float* src = &g[((size_t)t*2048 + bn)*64 + c0];
        float f8[8];
        *(float4*)f8 = *(const float4*)src;
        *(float4*)(f8+4) = *(const float4*)(src+4);
        uint4 hi, lo; split8(f8, hi, lo);
        int uu = (tid & 7) ^ (t & 7);
        *(uint4*)&sh[t][uu*8] = hi;
        *(uint4*)&sl[t][uu*8] = lo;
    }
    __syncthreads();
    int w = tid >> 6, l = tid & 63, lm = l & 15, ld = l >> 4;
    int co = w*16 + lm;
    f32x4 acc0 = {0.f,0.f,0.f,0.f}, acc1 = {0.f,0.f,0.f,0.f};
    const s16x8 zf = {0,0,0,0,0,0,0,0};
    for (int kc = 0; kc < K32; ++kc) {
        int ka = kc >> 1;
        int ci = (kc & 1)*32 + ld*8;
        s16x8 yh = *(const s16x8*)&wch[(size_t)co*K + kc*32 + ld*8];
        s16x8 yl = *(const s16x8*)&wcl[(size_t)co*K + kc*32 + ld*8];
        #pragma unroll
        for (int Mt = 0; Mt < 2; ++Mt) {
            int ts = Mt*16 + lm + ka - P;
            bool ok = ((unsigned)ts) < 32u;
            int tc = ok ? ts : 0;
            int ua = (ci >> 3) ^ (tc & 7);
            s16x8 xh = *(const s16x8*)&sh[tc][ua*8];
            s16x8 xl = *(const s16x8*)&sl[tc][ua*8];
            if (!ok) { xh = zf; xl = zf; }
            f32x4& a = Mt ? acc1 : acc0;
            a = __builtin_amdgcn_mfma_f32_16x16x32_bf16(xh, yh, a, 0, 0, 0);
            a = __builtin_amdgcn_mfma_f32_16x16x32_bf16(xh, yl, a, 0, 0, 0);
            a = __builtin_amdgcn_mfma_f32_16x16x32_bf16(xl, yh, a, 0, 0, 0);
        }
    }
    float bias = cb[co];
    if (LAST) {
        int b = bn >> 6, n = bn & 63;
        ush* ob = fo + (size_t)b*KFLAT + n*2048 + co*32;
        #pragma unroll
        for (int Mt = 0; Mt < 2; ++Mt) {
            const f32x4& a = Mt ? acc1 : acc0;
            ush hv[4];
            #pragma unroll
            for (int r = 0; r < 4; ++r) {
                float val = a[r] + bias;
                val = (val >= 0.f) ? val : 0.01f*val;
                hv[r] = f2bf(val);
            }
            *(uint2*)&ob[Mt*16 + ld*4] = make_uint2(hv[0]|(hv[1]<<16), hv[2]|(hv[3]<<16));
        }
    } else {
        #pragma unroll
        for (int Mt = 0; Mt < 2; ++Mt) {
            const f32x4& a = Mt ? acc1 : acc0;
            #pragma unroll
            for (int r = 0; r < 4; ++r) {
                int t = Mt*16 + ld*4 + r;
                float val = a[r] + bias;
                val = (val >= 0.f) ? val : 0.01f*val;
                g[((size_t)t*2048 + bn)*64 + co] = val;
            }
        }
    }
}

// ---------------- final GEMM via MFMA: async LDS staging, W-hi-only --------
// out[b][o] += sum_k flat[b][k] * W[o][k].  Grid: 12 og x 64 kc = 768 blocks.
// Double-buffered LDS tiles staged by global_load_lds; vmcnt(5) counted wait
// (5 loads/tile/wave). W treated bf16-hi only (absmax ~3.9e-3, thr 1.08e-2).
__global__ __launch_bounds__(256) void gemm_mfma(const ush* __restrict__ flat,
                                                 const float* __restrict__ W,
                                                 float* __restrict__ out)
{
    __shared__ __align__(16) float Wl[2][64][64];   // 32 KB
    __shared__ __align__(16) ush Al[2][32][64];     // 8 KB
    const int tid = threadIdx.x;
    const int w = tid >> 6, l = tid & 63;
    const int og = blockIdx.x >> 6;
    const int kc = blockIdx.x & 63;
    const int o_blk = og * 64;
    const int kbase = kc * 2048;

    const int wrow_l = l >> 4;
    const int wu = l & 15;
    size_t w_off[4];
    #pragma unroll
    for (int i = 0; i < 4; ++i) {
        int row = w*16 + i*4 + wrow_l;
        w_off[i] = (size_t)(o_blk + row) * KFLAT + (unsigned)((wu ^ (row & 7)) * 4);
    }
    const int arow = w*8 + (l >> 3);
    const int au = l & 7;
    const size_t a_off0 = (size_t)arow * KFLAT + (unsigned)((au ^ (arow & 7)) * 8);

#define ISSUE_TILE(buf_, s_) { \
    int kwin_ = kbase + (s_)*64; \
    _Pragma("unroll") \
    for (int i_ = 0; i_ < 4; ++i_) \
        gl2lds16(W + w_off[i_] + kwin_, &Wl[buf_][w*16 + i_*4][0]); \
    gl2lds16(flat + a_off0 + kwin_, &Al[buf_][w*8][0]); \
}

    f32x4 acc0 = {0.f,0.f,0.f,0.f}, acc1 = {0.f,0.f,0.f,0.f};
    ISSUE_TILE(0, 0);
    ISSUE_TILE(1, 1);

    const int lmod = l & 15, ldiv = l >> 4, lx = l & 7;
    for (int s = 0; s < 32; ++s) {
        if (s < 31) { asm volatile("s_waitcnt vmcnt(5)" ::: "memory"); }
        else        { asm volatile("s_waitcnt vmcnt(0)" ::: "memory"); }
        __builtin_amdgcn_s_barrier();
        asm volatile("" ::: "memory");
        const int cur = s & 1;
        #pragma unroll
        for (int ksub = 0; ksub < 2; ++ksub) {
            int ju = ksub*8 + ldiv*2;
            const float4 b0 = *(const float4*)&Wl[cur][w*16 + lmod][(ju ^ lx)*4];
            const float4 b1 = *(const float4*)&Wl[cur][w*16 + lmod][((ju+1) ^ lx)*4];
            float bf[8] = {b0.x,b0.y,b0.z,b0.w,b1.x,b1.y,b1.z,b1.w};
            s16x8 bhi;
            #pragma unroll
            for (int i = 0; i < 8; ++i) bhi[i] = (short)f2bf(bf[i]);
            int jua = ksub*4 + ldiv;
            const s16x8 a0 = *(const s16x8*)&Al[cur][lmod]      [(jua ^ lx)*8];
            const s16x8 a1 = *(const s16x8*)&Al[cur][16 + lmod] [(jua ^ lx)*8];
            acc0 = __builtin_amdgcn_mfma_f32_16x16x32_bf16(a0, bhi, acc0, 0, 0, 0);
            acc1 = __builtin_amdgcn_mfma_f32_16x16x32_bf16(a1, bhi, acc1, 0, 0, 0);
        }
        asm volatile("" ::: "memory");
        __builtin_amdgcn_s_barrier();
        if (s < 30) { ISSUE_TILE(cur, s+2); }
    }
#undef ISSUE_TILE

    const int o_out = o_blk + w*16 + lmod;
    #pragma unroll
    for (int r = 0; r < 4; ++r) {
        int b0_ = ldiv*4 + r;
        atomicAdd(&out[(size_t)b0_*OUTD + o_out], acc0[r]);
        atomicAdd(&out[(size_t)(16 + b0_)*OUTD + o_out], acc1[r]);
    }
}

extern "C" void kernel_launch(void* const* d_in, const int* in_sizes, int n_in,
                              void* d_out, int out_size, void* d_ws, size_t ws_size,
                              hipStream_t stream) {
    (void)in_sizes; (void)n_in; (void)out_size; (void)ws_size;
    const float* x        = (const float*)d_in[0];
    const float* w_x2i    = (const float*)d_in[1];
    const float* b_x2i    = (const float*)d_in[2];
    const float* gru_wih  = (const float*)d_in[3];
    const float* gru_whh  = (const float*)d_in[4];
    const float* gru_bih  = (const float*)d_in[5];
    const float* gru_bhh  = (const float*)d_in[6];
    const float* wq_w     = (const float*)d_in[7];
    const float* wq_b     = (const float*)d_in[8];
    const float* wk_w     = (const float*)d_in[9];
    const float* wk_b     = (const float*)d_in[10];
    const float* gcn_w[3]  = {(const float*)d_in[11], (const float*)d_in[15], (const float*)d_in[19]};
    const float* gcn_b[3]  = {(const float*)d_in[12], (const float*)d_in[16], (const float*)d_in[20]};
    const float* conv_w[3] = {(const float*)d_in[13], (const float*)d_in[17], (const float*)d_in[21]};
    const float* conv_b[3] = {(const float*)d_in[14], (const float*)d_in[18], (const float*)d_in[22]};
    const float* lout_w   = (const float*)d_in[23];
    const float* lout_b   = (const float*)d_in[24];
    float* out = (float*)d_out;
    float* ws  = (float*)d_ws;

    float* hT   = ws;                        // 131072
    float* u    = ws + 131072;               // 2048
    float* v    = ws + 133120;               // 2048
    float* bufA = ws + 135168;               // 4194304
    float* bufB = bufA + 4194304;            // 4194304  (ends 8523776 floats)
    ush* usb = (ush*)(ws + 8523776);
    ush* whT_hi  = usb;                      // 131072
    ush* whT_lo  = usb + 131072;
    ush* gwT1_hi = usb + 262144;
    ush* gwT1_lo = usb + 393216;
    ush* gwT2_hi = usb + 524288;
    ush* gwT2_lo = usb + 655360;
    ush* cw2_hi  = usb + 786432;             // 20480
    ush* cw2_lo  = usb + 806912;
    ush* cw3_hi  = usb + 827392;             // 28672
    ush* cw3_lo  = usb + 856064;             // ends 884736
    ush* cw1_hi  = usb + 884736;             // 12288
    ush* cw1_lo  = usb + 897024;             // ends 909312

    prep_gru_kernel<<<dim3(512), dim3(256), 0, stream>>>(
        x, gru_wih, gru_whh, gru_bih, gru_bhh, hT,
        gcn_w[0], w_x2i, b_x2i, u, v,
        gcn_w[1], gwT1_hi, gwT1_lo,
        gcn_w[2], gwT2_hi, gwT2_lo,
        conv_w[0], cw1_hi, cw1_lo,
        conv_w[1], cw2_hi, cw2_lo,
        conv_w[2], cw3_hi, cw3_lo,
        lout_b, out);
    attn_kernel<<<dim3(32), dim3(256), 0, stream>>>(hT, wq_w, wq_b, wk_w, wk_b, whT_hi, whT_lo);

    unsigned short* flat16 = (unsigned short*)bufB;
    gcn_mfma<true><<<dim3(1024), dim3(256), 0, stream>>>(x, nullptr, nullptr, u, v,
                                                         whT_hi, whT_lo, gcn_b[0], bufA);
    conv_mfma<3,false><<<dim3(2048), dim3(256), 0, stream>>>(bufA, cw1_hi, cw1_lo, conv_b[0], nullptr);
    gcn_mfma<false><<<dim3(1024), dim3(256), 0, stream>>>(bufA, gwT1_hi, gwT1_lo, u, v,
                                                          whT_hi, whT_lo, gcn_b[1], bufB);
    conv_mfma<5,false><<<dim3(2048), dim3(256), 0, stream>>>(bufB, cw2_hi, cw2_lo, conv_b[1], nullptr);
    gcn_mfma<false><<<dim3(1024), dim3(256), 0, stream>>>(bufB, gwT2_hi, gwT2_lo, u, v,
                                                          whT_hi, whT_lo, gcn_b[2], bufA);
    conv_mfma<7,true><<<dim3(2048), dim3(256), 0, stream>>>(bufA, cw3_hi, cw3_lo, conv_b[2], flat16);

    gemm_mfma<<<dim3(768), dim3(256), 0, stream>>>(flat16, lout_w, out);
}